// Round 7
// baseline (902.219 us; speedup 1.0000x reference)
//
#include <hip/hip_runtime.h>
#include <math.h>

#define A_TOTAL 61380
#define NGT 32
#define PTOT 21472   // padded pixels per batch: 96+308+1092+4100+15876

typedef _Float16 f16;
typedef f16 f16x8 __attribute__((ext_vector_type(8)));
typedef float f32x4 __attribute__((ext_vector_type(4)));

__device__ __constant__ int LV_H[5]    = {6, 12, 24, 48, 96};
__device__ __constant__ int LV_W[5]    = {10, 20, 40, 80, 160};
__device__ __constant__ int LV_PB[5]   = {0, 96, 404, 1496, 5596};  // padded bases
__device__ __constant__ int LV_TX[5]   = {1, 2, 3, 5, 10};          // ceil(W/16)

// async 16B global->LDS copy (DMA; LDS dest = wave-uniform base + lane*16)
typedef __attribute__((address_space(1))) const void* gptr_t;
typedef __attribute__((address_space(3))) void* lptr_t;
__device__ __forceinline__ void cp16_g2l(const void* g, void* l) {
  __builtin_amdgcn_global_load_lds((gptr_t)g, (lptr_t)l, 16, 0, 0);
}

// Tower tile map: 8-row x 16-col tiles. tiles/level = {1,4,9,30,120}, cum {0,1,5,14,44,164}
__device__ __forceinline__ void get_tile8(int t, int& lv, int& y0, int& x0)
{
  int local;
  if (t >= 44)      { lv = 4; local = t - 44; }
  else if (t >= 14) { lv = 3; local = t - 14; }
  else if (t >= 5)  { lv = 2; local = t - 5; }
  else if (t >= 1)  { lv = 1; local = t - 1; }
  else              { lv = 0; local = 0; }
  int tX = LV_TX[lv];
  y0 = (local / tX) * 8;
  x0 = (local % tX) * 16;
}

// Head tile map: 16x16 tiles. tiles/level = {1,2,6,15,60}, cum {0,1,3,9,24,84}
__device__ __forceinline__ void get_tile16(int t, int& lv, int& y0, int& x0)
{
  int local;
  if (t >= 24)      { lv = 4; local = t - 24; }
  else if (t >= 9)  { lv = 3; local = t - 9; }
  else if (t >= 3)  { lv = 2; local = t - 3; }
  else if (t >= 1)  { lv = 1; local = t - 1; }
  else              { lv = 0; local = 0; }
  int tX = LV_TX[lv];
  y0 = (local / tX) * 16;
  x0 = (local % tX) * 16;
}

// unpadded global pixel -> per-batch padded offset
__device__ __forceinline__ int padded_off(int p)
{
  if (p >= 5100)      { int po = p - 5100; int y = po / 160, x = po - y * 160; return 5596 + (y + 1) * 162 + x + 1; }
  else if (p >= 1260) { int po = p - 1260; int y = po / 80,  x = po - y * 80;  return 1496 + (y + 1) * 82  + x + 1; }
  else if (p >= 300)  { int po = p - 300;  int y = po / 40,  x = po - y * 40;  return 404  + (y + 1) * 42  + x + 1; }
  else if (p >= 60)   { int po = p - 60;   int y = po / 20,  x = po - y * 20;  return 96   + (y + 1) * 22  + x + 1; }
  else                { int y = p / 10, x = p - y * 10;                         return (y + 1) * 12 + x + 1; }
}

// ---------------------------------------------------------------------------
// Zero the 1-px borders of all 4 padded activation buffers (run first; the
// harness poisons d_ws each call). grid (1012, 2 batch, 4 buf), block 64.
// ---------------------------------------------------------------------------
__global__ __launch_bounds__(64) void zero_borders(f16* __restrict__ act)
{
  int e = blockIdx.x, b = blockIdx.y, z = blockIdx.z;
  int lv, e0;
  if (e >= 496)      { lv = 4; e0 = e - 496; }
  else if (e >= 236) { lv = 3; e0 = e - 236; }
  else if (e >= 104) { lv = 2; e0 = e - 104; }
  else if (e >= 36)  { lv = 1; e0 = e - 36; }
  else               { lv = 0; e0 = e; }
  int Hp = LV_H[lv] + 2, Wp = LV_W[lv] + 2;
  int y, x;
  if (e0 < Wp)          { y = 0;      x = e0; }
  else if (e0 < 2 * Wp) { y = Hp - 1; x = e0 - Wp; }
  else { int e2 = e0 - 2 * Wp; y = 1 + (e2 >> 1); x = (e2 & 1) ? (Wp - 1) : 0; }
  f16* dst = act + ((size_t)z * 2 * PTOT + (size_t)b * PTOT + LV_PB[lv] + y * Wp + x) * 256
           + threadIdx.x * 4;
  *(uint2*)dst = (uint2){0u, 0u};
}

// ---------------------------------------------------------------------------
// NCHW fp32 feats -> padded NHWC f16 (LDS transpose). grid (640, 8, 2).
// ---------------------------------------------------------------------------
__global__ __launch_bounds__(256) void feats_to_nhwc(
    const float* __restrict__ f0, const float* __restrict__ f1,
    const float* __restrict__ f2, const float* __restrict__ f3,
    const float* __restrict__ f4, f16* __restrict__ act)
{
  const int b = blockIdx.z;
  const int c0 = blockIdx.y * 32;
  const int p0 = blockIdx.x * 32;
  const int tx = threadIdx.x & 31, ty = threadIdx.x >> 5;
  __shared__ float tl[32][33];

  int p = p0 + tx;
  const float* src = f0; int po = 0;
  if (p >= 5100)      { src = f4; po = p - 5100; }
  else if (p >= 1260) { src = f3; po = p - 1260; }
  else if (p >= 300)  { src = f2; po = p - 300;  }
  else if (p >= 60)   { src = f1; po = p - 60;   }
  else                { src = f0; po = p;        }
  int HW = (p >= 5100) ? 15360 : (p >= 1260) ? 3840 : (p >= 300) ? 960 : (p >= 60) ? 240 : 60;

#pragma unroll
  for (int k = 0; k < 4; ++k) {
    int c = c0 + ty + k * 8;
    float v = 0.f;
    if (p < 20460) v = src[((size_t)b * 256 + c) * HW + po];
    tl[ty + k * 8][tx] = v;
  }
  __syncthreads();
#pragma unroll
  for (int k = 0; k < 4; ++k) {
    int pp = p0 + ty + k * 8;
    if (pp < 20460)
      act[((size_t)b * PTOT + padded_off(pp)) * 256 + c0 + tx] = (f16)tl[tx][ty + k * 8];
  }
}

// ---------------------------------------------------------------------------
// Tower weights fp32 [l][co][ci][9] -> f16 [l][tap][ci/8][co][8]
// ---------------------------------------------------------------------------
__global__ __launch_bounds__(256) void prep_tower_w3(
    const float* __restrict__ cls_w, const float* __restrict__ box_w,
    f16* __restrict__ wT)
{
  int blk = blockIdx.x;
  int l = blk >> 8, co = blk & 255;
  const float* src = (l < 4 ? cls_w + (size_t)l * 589824
                            : box_w + (size_t)(l - 4) * 589824)
                   + (size_t)co * 2304;
  __shared__ f16 sm[2304];                    // [ci][tap]
  int t = threadIdx.x;
#pragma unroll
  for (int j = 0; j < 9; ++j) sm[t + j * 256] = (f16)src[t + j * 256];
  __syncthreads();
#pragma unroll
  for (int it = 0; it < 2; ++it) {
    int c = t + it * 256;
    if (c < 288) {
      int tap = c >> 5, s = c & 31;
      f16x8 v;
#pragma unroll
      for (int e = 0; e < 8; ++e) v[e] = sm[(s * 8 + e) * 9 + tap];
      *(f16x8*)(wT + ((((size_t)l * 9 + tap) * 32 + s) * 256 + co) * 8) = v;
    }
  }
}

// Head weights -> f16 [pair][tap][ci/8][co32][8] (zero-padded co) + bias hb[2][32]
__global__ void prep_head_w3(const float* __restrict__ sw, const float* __restrict__ nw,
                             const float* __restrict__ bw, const float* __restrict__ iw,
                             const float* __restrict__ sb, const float* __restrict__ nb2,
                             const float* __restrict__ bb, const float* __restrict__ ib,
                             f16* __restrict__ wH, float* __restrict__ hb)
{
  int idx = blockIdx.x * 256 + threadIdx.x;   // 2*9*32*32 = 18432 units
  if (idx < 18432) {
    int p = idx / 9216, rem = idx - p * 9216;
    int tap = rem / 1024, rem2 = rem - tap * 1024;
    int s = rem2 >> 5, co = rem2 & 31;
    int C1 = p ? 24 : 6;
    const float* w1 = p ? bw : sw;
    const float* w2 = p ? iw : nw;
    f16x8 v;
#pragma unroll
    for (int e = 0; e < 8; ++e) {
      int ci = s * 8 + e;
      float x = 0.f;
      if (co < C1)          x = w1[((size_t)co * 256 + ci) * 9 + tap];
      else if (co < C1 + 6) x = w2[((size_t)(co - C1) * 256 + ci) * 9 + tap];
      v[e] = (f16)x;
    }
    *(f16x8*)(wH + (size_t)idx * 8) = v;
  }
  if (idx < 64) {
    int pp = idx >> 5, jj = idx & 31;
    int C1b = pp ? 24 : 6;
    const float* b1 = pp ? bb : sb;
    const float* b2 = pp ? ib : nb2;
    float bv = 0.f;
    if (jj < C1b)          bv = b1[jj];
    else if (jj < C1b + 6) bv = b2[jj - C1b];
    hb[idx] = bv;
  }
}

// ---------------------------------------------------------------------------
// MFMA tower conv v4: block 4 waves, tile 128px(8r x 16c) x 128co; wave tile
// 64x64 (acc 64 VGPRs -> ~100 regs spare for compiler pipelining at 2
// waves/SIMD). B for taps 0..7 of each ci-block DMA-staged into one 64 KB
// LDS buffer (2 barriers per ci-block, 16 total); tap 8's B read direct from
// L2. A direct from padded global NHWC (zero halo, no bounds checks).
// grid (164 tiles, 2 batch, 4 = tower*2+cogroup) = 1312 blocks (85% tail eff).
// ---------------------------------------------------------------------------
__global__ __launch_bounds__(256, 2) void conv_mfma_tower4(
    const f16* __restrict__ in_cls, f16* __restrict__ out_cls,
    const f16* __restrict__ in_box, f16* __restrict__ out_box,
    const f16* __restrict__ wT, const float* __restrict__ cls_b,
    const float* __restrict__ box_b, int layer)
{
  int lv, y0, x0;
  get_tile8(blockIdx.x, lv, y0, x0);
  const int H = LV_H[lv], W = LV_W[lv], Wp = W + 2, pbase = LV_PB[lv];
  const int b = blockIdx.y;
  const int z = blockIdx.z, tw = z >> 1, cog = z & 1;
  const f16* in  = tw ? in_box : in_cls;
  f16*       out = tw ? out_box : out_cls;
  const f16* wB = wT + (size_t)(tw * 4 + layer) * 2304 * 256;  // [tap][s][co][8]
  const float* bias = (tw ? box_b : cls_b) + layer * 256;

  const int tid = threadIdx.x;
  const int lane = tid & 63, wid = tid >> 6;
  const int m = lane & 15, q = lane >> 4;
  const int mrow = (wid & 1) * 4;          // 0 or 4 (row group)
  const int ncol = (wid >> 1) * 64;        // 0 or 64 (col group within 128)

  __shared__ __align__(16) f16 Bs[4096 * 8];  // taps 0..7: [tap][s0..3][c0..127]

  f32x4 acc[4][4];
#pragma unroll
  for (int i = 0; i < 4; ++i)
#pragma unroll
    for (int j = 0; j < 4; ++j) acc[i][j] = (f32x4){0.f, 0.f, 0.f, 0.f};

  const f16* inb = in + (size_t)(b * PTOT + pbase) * 256;
  const f16* pA = inb + ((size_t)(y0 + mrow) * Wp + x0 + m) * 256 + q * 8;

  for (int cb = 0; cb < 8; ++cb) {
    __syncthreads();              // prior reads of Bs done
    // DMA-stage B taps 0..7: 4096 units, 16 per thread. Dest unit = u (lane-
    // linear per wave); src = [tap*32 + cb*4 + s][co 128-run] (coalesced).
#pragma unroll
    for (int it = 0; it < 16; ++it) {
      int u = tid + it * 256;
      int tap = u >> 9, r = u & 511;
      int s = r >> 7, c = r & 127;
      cp16_g2l(wB + (((size_t)(tap * 32 + cb * 4 + s)) * 256 + cog * 128 + c) * 8,
               Bs + (size_t)u * 8);
    }
    __syncthreads();              // DMA complete (vmcnt drained by barrier)
    const f16* pAc = pA + cb * 32;
#pragma unroll
    for (int tap = 0; tap < 9; ++tap) {
      const int ky = tap / 3, kx = tap - ky * 3;
      f16x8 af[4], bf[4];
#pragma unroll
      for (int mb = 0; mb < 4; ++mb)
        af[mb] = *(const f16x8*)(pAc + ((size_t)(mb + ky) * Wp + kx) * 256);
      if (tap < 8) {
#pragma unroll
        for (int nb = 0; nb < 4; ++nb)
          bf[nb] = *(const f16x8*)(Bs + (size_t)(tap * 512 + q * 128 + ncol + nb * 16 + m) * 8);
      } else {
#pragma unroll
        for (int nb = 0; nb < 4; ++nb)
          bf[nb] = *(const f16x8*)(wB + (((size_t)(256 + cb * 4 + q)) * 256 + cog * 128 + ncol + nb * 16 + m) * 8);
      }
#pragma unroll
      for (int mb = 0; mb < 4; ++mb)
#pragma unroll
        for (int nb = 0; nb < 4; ++nb)
          acc[mb][nb] = __builtin_amdgcn_mfma_f32_16x16x32_f16(af[mb], bf[nb], acc[mb][nb], 0, 0, 0);
    }
  }

  // epilogue: D row (q*4+r) = x-offset, col (m) = co; write padded interior
  f16* outb = out + (size_t)(b * PTOT + pbase) * 256;
#pragma unroll
  for (int mb = 0; mb < 4; ++mb) {
    int y = y0 + mrow + mb;
    if (y >= H) continue;
#pragma unroll
    for (int nb = 0; nb < 4; ++nb) {
      int co = cog * 128 + ncol + nb * 16 + m;
      float bi = bias[co];
#pragma unroll
      for (int r = 0; r < 4; ++r) {
        int x = x0 + q * 4 + r;
        if (x < W) {
          float v = fmaxf(acc[mb][nb][r] + bi, 0.f);
          outb[((size_t)(y + 1) * Wp + x + 1) * 256 + co] = (f16)v;
        }
      }
    }
  }
}

// ---------------------------------------------------------------------------
// Merged MFMA head pairs, NO LDS / NO BARRIERS. grid (84, 2, 2), block 256.
// ---------------------------------------------------------------------------
__global__ __launch_bounds__(256) void conv_mfma_head3(
    const f16* __restrict__ in_cls, const f16* __restrict__ in_box,
    const f16* __restrict__ wH, const float* __restrict__ hb,
    float* __restrict__ cls_prob, float* __restrict__ num_prob,
    float* __restrict__ offsets, float* __restrict__ iou_prob)
{
  int lv, y0, x0;
  get_tile16(blockIdx.x, lv, y0, x0);
  const int H = LV_H[lv], W = LV_W[lv], Wp = W + 2, pbase = LV_PB[lv];
  const int b = blockIdx.y, z = blockIdx.z;
  const f16* in = z ? in_box : in_cls;
  const f16* wB = wH + (size_t)z * 2304 * 32;   // [tap][s][co32][8]
  const float* hbz = hb + z * 32;
  float* o1 = z ? offsets : cls_prob;
  float* o2 = z ? iou_prob : num_prob;
  const int C1 = z ? 24 : 6, P1 = z ? 8 : 2, SIG = z ? 0 : 1;

  const int tid = threadIdx.x;
  const int lane = tid & 63, wid = tid >> 6;
  const int m = lane & 15, q = lane >> 4;

  f32x4 acc[4][2];
#pragma unroll
  for (int i = 0; i < 4; ++i) { acc[i][0] = (f32x4){0,0,0,0}; acc[i][1] = (f32x4){0,0,0,0}; }

  const f16* inb = in + (size_t)(b * PTOT + pbase) * 256;
  const f16* pA = inb + ((size_t)(y0 + wid * 4) * Wp + x0 + m) * 256 + q * 8;
  const f16* pB = wB + ((size_t)q * 32 + m) * 8;

  for (int cb = 0; cb < 8; ++cb) {
    const f16* pAc = pA + cb * 32;
    const f16* pBc = pB + (size_t)cb * 4 * 32 * 8;
#pragma unroll
    for (int tap = 0; tap < 9; ++tap) {
      const int ky = tap / 3, kx = tap - ky * 3;
      f16x8 af[4], bf[2];
#pragma unroll
      for (int mb = 0; mb < 4; ++mb)
        af[mb] = *(const f16x8*)(pAc + ((size_t)(mb + ky) * Wp + kx) * 256);
#pragma unroll
      for (int nb = 0; nb < 2; ++nb)
        bf[nb] = *(const f16x8*)(pBc + (size_t)tap * 8192 + nb * 128);
#pragma unroll
      for (int mb = 0; mb < 4; ++mb)
#pragma unroll
        for (int nb = 0; nb < 2; ++nb)
          acc[mb][nb] = __builtin_amdgcn_mfma_f32_16x16x32_f16(af[mb], bf[nb], acc[mb][nb], 0, 0, 0);
    }
  }

  const int robase = (lv == 0 ? 0 : lv == 1 ? 60 : lv == 2 ? 300 : lv == 3 ? 1260 : 5100) * 3;
#pragma unroll
  for (int mb = 0; mb < 4; ++mb) {
    int y = y0 + wid * 4 + mb;
    if (y >= H) continue;
#pragma unroll
    for (int nb = 0; nb < 2; ++nb) {
      int j = nb * 16 + m;
      if (j >= C1 + 6) continue;
      float bi = hbz[j];
#pragma unroll
      for (int r = 0; r < 4; ++r) {
        int x = x0 + q * 4 + r;
        if (x < W) {
          float v = acc[mb][nb][r] + bi;
          int row0 = robase + (y * W + x) * 3;
          if (j < C1) {
            if (SIG) v = 1.f / (1.f + expf(-v));
            int jd = j / P1;
            o1[((size_t)b * A_TOTAL + row0 + jd) * P1 + (j - jd * P1)] = v;
          } else {
            int jj = j - C1;
            o2[((size_t)b * A_TOTAL + row0 + (jj >> 1)) * 2 + (jj & 1)] = v;
          }
        }
      }
    }
  }
}

// ---------------------------------------------------------------------------
// Anchor generation (exact in fp32); also zeroes the loss accumulator.
// ---------------------------------------------------------------------------
__global__ void gen_anchors(float* __restrict__ anchors, float* __restrict__ accum)
{
  int i = blockIdx.x * 256 + threadIdx.x;
  if (blockIdx.x == 0 && threadIdx.x < 8) accum[threadIdx.x] = 0.f;
  if (i >= A_TOTAL) return;
  int off, s, Wl;
  if (i >= 15300)     { off = 15300; s = 8;   Wl = 160; }
  else if (i >= 3780) { off = 3780;  s = 16;  Wl = 80;  }
  else if (i >= 900)  { off = 900;   s = 32;  Wl = 40;  }
  else if (i >= 180)  { off = 180;   s = 64;  Wl = 20;  }
  else                { off = 0;     s = 128; Wl = 10;  }
  int r = i - off;
  int cell = r / 3, a = r - cell * 3;
  int y = cell / Wl, x = cell - y * Wl;
  float wsv = (a == 0) ? 4.f : (a == 1) ? 3.f : 2.f;
  float hsv = (a == 0) ? 4.f : 6.f;
  float sw = wsv * (float)s, sh = hsv * (float)s;
  float cx = (float)(x * s) + 1.5f, cy = (float)(y * s) + 1.5f;
  anchors[i * 4 + 0] = cx - 0.5f * (sw - 1.f);
  anchors[i * 4 + 1] = cy - 0.5f * (sh - 1.f);
  anchors[i * 4 + 2] = cx + 0.5f * (sw - 1.f);
  anchors[i * 4 + 3] = cy + 0.5f * (sh - 1.f);
}

__global__ __launch_bounds__(256) void anchor_target(
    const float* __restrict__ anchors, const float* __restrict__ gt,
    const float* __restrict__ iminfo, float* __restrict__ rpn, float* __restrict__ tgt)
{
  int i = blockIdx.x * 256 + threadIdx.x;
  int b = blockIdx.y;
  if (i >= A_TOTAL) return;
  float cnt = iminfo[b * 6 + 5];
  float ax1 = anchors[i*4+0], ay1 = anchors[i*4+1], ax2 = anchors[i*4+2], ay2 = anchors[i*4+3];
  float aw = ax2 - ax1 + 1.f, ah = ay2 - ay1 + 1.f, ab = aw * ah;
  float v1 = -1e30f, v2 = -1e30f; int i1 = 0, i2 = 0;
  for (int g = 0; g < NGT; ++g) {
    const float* gp = gt + (b * NGT + g) * 5;
    float ov = -1.f;
    if ((float)g < cnt && gp[4] != -1.f) {
      float iw = fmaxf(fminf(ax2, gp[2]) - fmaxf(ax1, gp[0]) + 1.f, 0.f);
      float ih = fmaxf(fminf(ay2, gp[3]) - fmaxf(ay1, gp[1]) + 1.f, 0.f);
      float inter = iw * ih;
      float ag = (gp[2] - gp[0] + 1.f) * (gp[3] - gp[1] + 1.f);
      ov = inter / (ab + ag - inter);
    }
    if (ov > v1)      { v2 = v1; i2 = i1; v1 = ov; i1 = g; }
    else if (ov > v2) { v2 = ov; i2 = g; }
  }
  float l1 = (v1 >= 0.5f) ? 1.f : ((v1 < 0.4f) ? 0.f : -1.f);
  float l2 = (v2 >= 0.5f) ? 1.f : ((v2 < 0.4f) ? 0.f : -1.f);
  rpn[(b * A_TOTAL + i) * 2 + 0] = l1;
  rpn[(b * A_TOTAL + i) * 2 + 1] = l2;
  float acx = ax1 + 0.5f * (aw - 1.f), acy = ay1 + 0.5f * (ah - 1.f);
  int idx2[2] = {i1, i2};
#pragma unroll
  for (int k = 0; k < 2; ++k) {
    const float* gp = gt + (b * NGT + idx2[k]) * 5;
    float gw = gp[2] - gp[0] + 1.f, gh = gp[3] - gp[1] + 1.f;
    float gcx = gp[0] + 0.5f * (gw - 1.f), gcy = gp[1] + 0.5f * (gh - 1.f);
    float* o = tgt + ((size_t)(b * 2 * A_TOTAL) + i * 2 + k) * 4;
    o[0] = (gcx - acx) / aw;  o[1] = (gcy - acy) / ah;
    o[2] = logf(gw / aw);     o[3] = logf(gh / ah);
  }
}

__global__ __launch_bounds__(256) void iou_target(
    const float* __restrict__ anchors, const float* __restrict__ gt,
    const float* __restrict__ iminfo, const float* __restrict__ offsets,
    float* __restrict__ ioust)
{
  int i = blockIdx.x * 256 + threadIdx.x;
  int b = blockIdx.y;
  if (i >= A_TOTAL) return;
  float cnt = iminfo[b * 6 + 5];
  float ax1 = anchors[i*4+0], ay1 = anchors[i*4+1], ax2 = anchors[i*4+2], ay2 = anchors[i*4+3];
  float aw = ax2 - ax1 + 1.f, ah = ay2 - ay1 + 1.f;
  float acx = ax1 + 0.5f * (aw - 1.f), acy = ay1 + 0.5f * (ah - 1.f);
  const float mx = 4.135166556742356f;
  float bx[2][4];
#pragma unroll
  for (int k = 0; k < 2; ++k) {
    const float* d = offsets + ((size_t)(b * A_TOTAL) + i) * 8 + k * 4;
    float pw = expf(fminf(d[2], mx)) * aw;
    float ph = expf(fminf(d[3], mx)) * ah;
    float pcx = d[0] * aw + acx, pcy = d[1] * ah + acy;
    bx[k][0] = pcx - 0.5f * (pw - 1.f); bx[k][1] = pcy - 0.5f * (ph - 1.f);
    bx[k][2] = pcx + 0.5f * (pw - 1.f); bx[k][3] = pcy + 0.5f * (ph - 1.f);
  }
  float area0 = (bx[0][2]-bx[0][0]+1.f) * (bx[0][3]-bx[0][1]+1.f);
  float area1 = (bx[1][2]-bx[1][0]+1.f) * (bx[1][3]-bx[1][1]+1.f);
  float av = -1e30f; int i1 = 0;
  for (int g = 0; g < NGT; ++g) {
    const float* gp = gt + (b * NGT + g) * 5;
    float keep = ((float)g < cnt && gp[4] != -1.f) ? 1.f : 0.f;
    float ag = (gp[2] - gp[0] + 1.f) * (gp[3] - gp[1] + 1.f);
    float iw = fmaxf(fminf(bx[0][2], gp[2]) - fmaxf(bx[0][0], gp[0]) + 1.f, 0.f);
    float ih = fmaxf(fminf(bx[0][3], gp[3]) - fmaxf(bx[0][1], gp[1]) + 1.f, 0.f);
    float inter = iw * ih;
    float ov = inter / (area0 + ag - inter) * keep;
    if (ov > av) { av = ov; i1 = g; }
  }
  float bv = -1e30f;
  for (int g = 0; g < NGT; ++g) {
    float val = 0.f;
    if (g != i1) {
      const float* gp = gt + (b * NGT + g) * 5;
      float keep = ((float)g < cnt && gp[4] != -1.f) ? 1.f : 0.f;
      float ag = (gp[2] - gp[0] + 1.f) * (gp[3] - gp[1] + 1.f);
      float iw = fmaxf(fminf(bx[1][2], gp[2]) - fmaxf(bx[1][0], gp[0]) + 1.f, 0.f);
      float ih = fmaxf(fminf(bx[1][3], gp[3]) - fmaxf(bx[1][1], gp[1]) + 1.f, 0.f);
      float inter = iw * ih;
      val = inter / (area1 + ag - inter) * keep;
    }
    bv = fmaxf(bv, val);
  }
  ioust[(b * A_TOTAL + i) * 2 + 0] = av;
  ioust[(b * A_TOTAL + i) * 2 + 1] = bv;
}

__global__ __launch_bounds__(256) void loss_reduce(
    const float* __restrict__ cls_prob, const float* __restrict__ num_prob,
    const float* __restrict__ offsets,  const float* __restrict__ iou_prob,
    const float* __restrict__ rpn,      const float* __restrict__ tgt,
    const float* __restrict__ ioust,    float* __restrict__ accum)
{
  int i = blockIdx.x * 256 + threadIdx.x;
  int b = blockIdx.y;
  float cls_s = 0.f, npos = 0.f, bb_s = 0.f, iou_s = 0.f, num_s = 0.f, num_c = 0.f;
  float la = 0.f, ign = 0.f;
  if (i < A_TOTAL) {
    int base = b * A_TOTAL + i;
    la = rpn[base * 2 + 0];
    float lb = rpn[base * 2 + 1];
    ign = lb - ((la == 0.f && lb != 0.f) ? 1.f : 0.f);
    float lab2[2] = {la, ign};
#pragma unroll
    for (int j = 0; j < 2; ++j) {
      float l = lab2[j];
      float mask = (l != -1.f) ? 1.f : 0.f;
      bool oh = (l * mask) == 1.f;
      float p = cls_prob[base * 2 + j];
      float term = oh ? (0.25f * (1.f - p) * (1.f - p) * logf(p))
                      : (0.75f * p * p * logf(1.f - p));
      cls_s += -term * mask;
      if (l > 0.f) {
        npos += 1.f;
#pragma unroll
        for (int c = 0; c < 4; ++c) {
          float d = offsets[(size_t)base * 8 + j * 4 + c]
                  - tgt[((size_t)(b * 2 * A_TOTAL) + i * 2 + j) * 4 + c];
          float ad = fabsf(d);
          bb_s += (ad < 1.f / 9.f) ? (4.5f * d * d) : (ad - 0.5f / 9.f);
        }
        iou_s += fabsf(iou_prob[base * 2 + j] - ioust[base * 2 + j]);
      }
    }
    int nl = ((la > 0.f) ? 1 : 0) + ((ign > 0.f) ? 1 : 0) - 1;
    if (nl != -1) {
      float s0 = num_prob[base * 2], s1 = num_prob[base * 2 + 1];
      float mm = fmaxf(s0, s1);
      float lse = mm + logf(expf(s0 - mm) + expf(s1 - mm));
      num_s += lse - ((nl == 0) ? s0 : s1);
      num_c += 1.f;
    }
  }
  __shared__ float red[6][4];
  float vals[6] = {cls_s, npos, bb_s, iou_s, num_s, num_c};
  int lane = threadIdx.x & 63, wid = threadIdx.x >> 6;
#pragma unroll
  for (int qq = 0; qq < 6; ++qq) {
    float v = vals[qq];
#pragma unroll
    for (int o = 32; o > 0; o >>= 1) v += __shfl_down(v, o);
    if (lane == 0) red[qq][wid] = v;
  }
  __syncthreads();
  if (threadIdx.x < 6) {
    float s = red[threadIdx.x][0] + red[threadIdx.x][1] + red[threadIdx.x][2] + red[threadIdx.x][3];
    atomicAdd(&accum[threadIdx.x], s);
  }
}

__global__ void finalize_loss(const float* __restrict__ acc, float* __restrict__ out)
{
  float npos = fmaxf(acc[1], 1.f);
  out[0] = acc[0] / npos;
  out[1] = 2.f * acc[2] / npos;
  out[2] = 2.f * acc[3] / npos;
  out[3] = acc[4] / fmaxf(acc[5], 1.f);
}

// ---------------------------------------------------------------------------
extern "C" void kernel_launch(void* const* d_in, const int* in_sizes, int n_in,
                              void* d_out, int out_size, void* d_ws, size_t ws_size,
                              hipStream_t stream)
{
  (void)in_sizes; (void)n_in; (void)out_size; (void)ws_size;
  const float* feat[5];
  for (int i = 0; i < 5; ++i) feat[i] = (const float*)d_in[i];
  const float* gt      = (const float*)d_in[5];
  const float* iminfo  = (const float*)d_in[6];
  const float* cls_w   = (const float*)d_in[7];
  const float* cls_b   = (const float*)d_in[8];
  const float* box_w   = (const float*)d_in[9];
  const float* box_b   = (const float*)d_in[10];
  const float* score_w = (const float*)d_in[11];
  const float* score_b = (const float*)d_in[12];
  const float* bpred_w = (const float*)d_in[13];
  const float* bpred_b = (const float*)d_in[14];
  const float* iou_w   = (const float*)d_in[15];
  const float* iou_b   = (const float*)d_in[16];
  const float* num_w   = (const float*)d_in[17];
  const float* num_b   = (const float*)d_in[18];

  const size_t ACT2 = (size_t)2 * PTOT * 256;      // padded activations, n=2
  f16* actF = (f16*)d_ws;                          // feats / box ping
  f16* actA = actF + ACT2;                         // cls ping (aliased later)
  f16* actB = actA + ACT2;                         // cls pong (cls tower out)
  f16* actC = actB + ACT2;                         // box pong
  f16* wT   = actC + ACT2;                         // 8*2304*256 f16
  f16* wH   = wT + (size_t)8 * 2304 * 256;         // 2*2304*32 f16
  float* hb = (float*)(wH + (size_t)2 * 2304 * 32);// 64 f32

  // loss-side buffers aliased into actA (dead after tower layer 3)
  float* cls_prob = (float*)actA;                  // 2*A*2
  float* num_prob = cls_prob + 2 * A_TOTAL * 2;
  float* offsets  = num_prob + 2 * A_TOTAL * 2;    // 2*A*8
  float* iou_prob = offsets + 2 * A_TOTAL * 8;
  float* anchors  = iou_prob + 2 * A_TOTAL * 2;    // A*4
  float* rpn      = anchors + A_TOTAL * 4;         // 2*A*2
  float* tgt      = rpn + 2 * A_TOTAL * 2;         // 2*2A*4
  float* ioust    = tgt + 2 * 2 * A_TOTAL * 4;     // 2*A*2
  float* accum    = ioust + 2 * A_TOTAL * 2;       // 8

  prep_tower_w3<<<dim3(2048), 256, 0, stream>>>(cls_w, box_w, wT);
  prep_head_w3<<<dim3(72), 256, 0, stream>>>(
      score_w, num_w, bpred_w, iou_w, score_b, num_b, bpred_b, iou_b, wH, hb);
  zero_borders<<<dim3(1012, 2, 4), 64, 0, stream>>>(actF);
  feats_to_nhwc<<<dim3(640, 8, 2), 256, 0, stream>>>(
      feat[0], feat[1], feat[2], feat[3], feat[4], actF);

  // merged towers: cls chain F->A->B->A->B ; box chain F->C->F->C->F
  dim3 tg(164, 2, 4);
  conv_mfma_tower4<<<tg, 256, 0, stream>>>(actF, actA, actF, actC, wT, cls_b, box_b, 0);
  conv_mfma_tower4<<<tg, 256, 0, stream>>>(actA, actB, actC, actF, wT, cls_b, box_b, 1);
  conv_mfma_tower4<<<tg, 256, 0, stream>>>(actB, actA, actF, actC, wT, cls_b, box_b, 2);
  conv_mfma_tower4<<<tg, 256, 0, stream>>>(actA, actB, actC, actF, wT, cls_b, box_b, 3);

  // merged heads: cls tower out = actB, box tower out = actF
  conv_mfma_head3<<<dim3(84, 2, 2), 256, 0, stream>>>(
      actB, actF, wH, hb, cls_prob, num_prob, offsets, iou_prob);

  dim3 agrid((A_TOTAL + 255) / 256, 2);
  gen_anchors<<<dim3((A_TOTAL + 255) / 256), 256, 0, stream>>>(anchors, accum);
  anchor_target<<<agrid, 256, 0, stream>>>(anchors, gt, iminfo, rpn, tgt);
  iou_target<<<agrid, 256, 0, stream>>>(anchors, gt, iminfo, offsets, ioust);
  loss_reduce<<<agrid, 256, 0, stream>>>(cls_prob, num_prob, offsets, iou_prob,
                                         rpn, tgt, ioust, accum);
  finalize_loss<<<1, 1, 0, stream>>>(accum, (float*)d_out);
}

// Round 8
// 733.060 us; speedup vs baseline: 1.2308x; 1.2308x over previous
//
#include <hip/hip_runtime.h>
#include <math.h>

#define A_TOTAL 61380
#define NGT 32
#define PTOT 21472   // padded pixels per batch: 96+308+1092+4100+15876

typedef _Float16 f16;
typedef f16 f16x8 __attribute__((ext_vector_type(8)));
typedef float f32x4 __attribute__((ext_vector_type(4)));

__device__ __constant__ int LV_H[5]    = {6, 12, 24, 48, 96};
__device__ __constant__ int LV_W[5]    = {10, 20, 40, 80, 160};
__device__ __constant__ int LV_PB[5]   = {0, 96, 404, 1496, 5596};  // padded bases
__device__ __constant__ int LV_TX[5]   = {1, 2, 3, 5, 10};          // ceil(W/16)

// async 16B global->LDS copy (DMA; LDS dest = wave-uniform base + lane*16)
typedef __attribute__((address_space(1))) const void* gptr_t;
typedef __attribute__((address_space(3))) void* lptr_t;
__device__ __forceinline__ void cp16_g2l(const void* g, void* l) {
  __builtin_amdgcn_global_load_lds((gptr_t)g, (lptr_t)l, 16, 0, 0);
}

// Tower tile map: 8-row x 16-col tiles. tiles/level = {1,4,9,30,120}, cum {0,1,5,14,44,164}
__device__ __forceinline__ void get_tile8(int t, int& lv, int& y0, int& x0)
{
  int local;
  if (t >= 44)      { lv = 4; local = t - 44; }
  else if (t >= 14) { lv = 3; local = t - 14; }
  else if (t >= 5)  { lv = 2; local = t - 5; }
  else if (t >= 1)  { lv = 1; local = t - 1; }
  else              { lv = 0; local = 0; }
  int tX = LV_TX[lv];
  y0 = (local / tX) * 8;
  x0 = (local % tX) * 16;
}

// Head tile map: 16x16 tiles. tiles/level = {1,2,6,15,60}, cum {0,1,3,9,24,84}
__device__ __forceinline__ void get_tile16(int t, int& lv, int& y0, int& x0)
{
  int local;
  if (t >= 24)      { lv = 4; local = t - 24; }
  else if (t >= 9)  { lv = 3; local = t - 9; }
  else if (t >= 3)  { lv = 2; local = t - 3; }
  else if (t >= 1)  { lv = 1; local = t - 1; }
  else              { lv = 0; local = 0; }
  int tX = LV_TX[lv];
  y0 = (local / tX) * 16;
  x0 = (local % tX) * 16;
}

// unpadded global pixel -> per-batch padded offset
__device__ __forceinline__ int padded_off(int p)
{
  if (p >= 5100)      { int po = p - 5100; int y = po / 160, x = po - y * 160; return 5596 + (y + 1) * 162 + x + 1; }
  else if (p >= 1260) { int po = p - 1260; int y = po / 80,  x = po - y * 80;  return 1496 + (y + 1) * 82  + x + 1; }
  else if (p >= 300)  { int po = p - 300;  int y = po / 40,  x = po - y * 40;  return 404  + (y + 1) * 42  + x + 1; }
  else if (p >= 60)   { int po = p - 60;   int y = po / 20,  x = po - y * 20;  return 96   + (y + 1) * 22  + x + 1; }
  else                { int y = p / 10, x = p - y * 10;                         return (y + 1) * 12 + x + 1; }
}

// ---------------------------------------------------------------------------
// Zero the 1-px borders of all 4 padded activation buffers.
// grid (1012, 2 batch, 4 buf), block 64.
// ---------------------------------------------------------------------------
__global__ __launch_bounds__(64) void zero_borders(f16* __restrict__ act)
{
  int e = blockIdx.x, b = blockIdx.y, z = blockIdx.z;
  int lv, e0;
  if (e >= 496)      { lv = 4; e0 = e - 496; }
  else if (e >= 236) { lv = 3; e0 = e - 236; }
  else if (e >= 104) { lv = 2; e0 = e - 104; }
  else if (e >= 36)  { lv = 1; e0 = e - 36; }
  else               { lv = 0; e0 = e; }
  int Hp = LV_H[lv] + 2, Wp = LV_W[lv] + 2;
  int y, x;
  if (e0 < Wp)          { y = 0;      x = e0; }
  else if (e0 < 2 * Wp) { y = Hp - 1; x = e0 - Wp; }
  else { int e2 = e0 - 2 * Wp; y = 1 + (e2 >> 1); x = (e2 & 1) ? (Wp - 1) : 0; }
  f16* dst = act + ((size_t)z * 2 * PTOT + (size_t)b * PTOT + LV_PB[lv] + y * Wp + x) * 256
           + threadIdx.x * 4;
  *(uint2*)dst = (uint2){0u, 0u};
}

// ---------------------------------------------------------------------------
// NCHW fp32 feats -> padded NHWC f16 (LDS transpose). grid (640, 8, 2).
// ---------------------------------------------------------------------------
__global__ __launch_bounds__(256) void feats_to_nhwc(
    const float* __restrict__ f0, const float* __restrict__ f1,
    const float* __restrict__ f2, const float* __restrict__ f3,
    const float* __restrict__ f4, f16* __restrict__ act)
{
  const int b = blockIdx.z;
  const int c0 = blockIdx.y * 32;
  const int p0 = blockIdx.x * 32;
  const int tx = threadIdx.x & 31, ty = threadIdx.x >> 5;
  __shared__ float tl[32][33];

  int p = p0 + tx;
  const float* src = f0; int po = 0;
  if (p >= 5100)      { src = f4; po = p - 5100; }
  else if (p >= 1260) { src = f3; po = p - 1260; }
  else if (p >= 300)  { src = f2; po = p - 300;  }
  else if (p >= 60)   { src = f1; po = p - 60;   }
  else                { src = f0; po = p;        }
  int HW = (p >= 5100) ? 15360 : (p >= 1260) ? 3840 : (p >= 300) ? 960 : (p >= 60) ? 240 : 60;

#pragma unroll
  for (int k = 0; k < 4; ++k) {
    int c = c0 + ty + k * 8;
    float v = 0.f;
    if (p < 20460) v = src[((size_t)b * 256 + c) * HW + po];
    tl[ty + k * 8][tx] = v;
  }
  __syncthreads();
#pragma unroll
  for (int k = 0; k < 4; ++k) {
    int pp = p0 + ty + k * 8;
    if (pp < 20460)
      act[((size_t)b * PTOT + padded_off(pp)) * 256 + c0 + tx] = (f16)tl[tx][ty + k * 8];
  }
}

// ---------------------------------------------------------------------------
// Tower weights fp32 [l][co][ci][9] -> f16 [l][tap][ci/8][co][8]
// ---------------------------------------------------------------------------
__global__ __launch_bounds__(256) void prep_tower_w3(
    const float* __restrict__ cls_w, const float* __restrict__ box_w,
    f16* __restrict__ wT)
{
  int blk = blockIdx.x;
  int l = blk >> 8, co = blk & 255;
  const float* src = (l < 4 ? cls_w + (size_t)l * 589824
                            : box_w + (size_t)(l - 4) * 589824)
                   + (size_t)co * 2304;
  __shared__ f16 sm[2304];                    // [ci][tap]
  int t = threadIdx.x;
#pragma unroll
  for (int j = 0; j < 9; ++j) sm[t + j * 256] = (f16)src[t + j * 256];
  __syncthreads();
#pragma unroll
  for (int it = 0; it < 2; ++it) {
    int c = t + it * 256;
    if (c < 288) {
      int tap = c >> 5, s = c & 31;
      f16x8 v;
#pragma unroll
      for (int e = 0; e < 8; ++e) v[e] = sm[(s * 8 + e) * 9 + tap];
      *(f16x8*)(wT + ((((size_t)l * 9 + tap) * 32 + s) * 256 + co) * 8) = v;
    }
  }
}

// Head weights -> f16 [pair][tap][ci/8][co32][8] (zero-padded co) + bias hb[2][32]
__global__ void prep_head_w3(const float* __restrict__ sw, const float* __restrict__ nw,
                             const float* __restrict__ bw, const float* __restrict__ iw,
                             const float* __restrict__ sb, const float* __restrict__ nb2,
                             const float* __restrict__ bb, const float* __restrict__ ib,
                             f16* __restrict__ wH, float* __restrict__ hb)
{
  int idx = blockIdx.x * 256 + threadIdx.x;   // 2*9*32*32 = 18432 units
  if (idx < 18432) {
    int p = idx / 9216, rem = idx - p * 9216;
    int tap = rem / 1024, rem2 = rem - tap * 1024;
    int s = rem2 >> 5, co = rem2 & 31;
    int C1 = p ? 24 : 6;
    const float* w1 = p ? bw : sw;
    const float* w2 = p ? iw : nw;
    f16x8 v;
#pragma unroll
    for (int e = 0; e < 8; ++e) {
      int ci = s * 8 + e;
      float x = 0.f;
      if (co < C1)          x = w1[((size_t)co * 256 + ci) * 9 + tap];
      else if (co < C1 + 6) x = w2[((size_t)(co - C1) * 256 + ci) * 9 + tap];
      v[e] = (f16)x;
    }
    *(f16x8*)(wH + (size_t)idx * 8) = v;
  }
  if (idx < 64) {
    int pp = idx >> 5, jj = idx & 31;
    int C1b = pp ? 24 : 6;
    const float* b1 = pp ? bb : sb;
    const float* b2 = pp ? ib : nb2;
    float bv = 0.f;
    if (jj < C1b)          bv = b1[jj];
    else if (jj < C1b + 6) bv = b2[jj - C1b];
    hb[idx] = bv;
  }
}

// ---------------------------------------------------------------------------
// MFMA tower conv v5: both fragment streams through the LDS pipe; only DMA
// touches the vector-mem (TA) pipe. Per ci-block (32 ci): DMA-stage A window
// (10r x 18px x 4seg = 720 units, 11.25 KB — padded halo makes this possible)
// and B taps 0..5 (3072 units, 48 KB) into LDS; taps 6..8 (ky=2) read B
// direct from L2. A-rows register-cached across ky (18 LDS af reads/cb, not
// 36). Block 128px x 128co, 4 waves of 64x64 (acc 64). 2 barriers per cb.
// LDS 60672 B -> 2 blocks/CU. grid (164, 2, 4=tower*2+cog) = 1312 blocks.
// ---------------------------------------------------------------------------
__global__ __launch_bounds__(256, 2) void conv_mfma_tower5(
    const f16* __restrict__ in_cls, f16* __restrict__ out_cls,
    const f16* __restrict__ in_box, f16* __restrict__ out_box,
    const f16* __restrict__ wT, const float* __restrict__ cls_b,
    const float* __restrict__ box_b, int layer)
{
  int lv, y0, x0;
  get_tile8(blockIdx.x, lv, y0, x0);
  const int H = LV_H[lv], W = LV_W[lv], Wp = W + 2, pbase = LV_PB[lv];
  const int b = blockIdx.y;
  const int z = blockIdx.z, tw = z >> 1, cog = z & 1;
  const f16* in  = tw ? in_box : in_cls;
  f16*       out = tw ? out_box : out_cls;
  const f16* wB = wT + (size_t)(tw * 4 + layer) * 2304 * 256;  // [tap][S][co][8]
  const float* bias = (tw ? box_b : cls_b) + layer * 256;

  const int tid = threadIdx.x;
  const int lane = tid & 63, wid = tid >> 6;
  const int m = lane & 15, q = lane >> 4;
  const int mrow = (wid & 1) * 4;          // 0 or 4 (pixel-row group)
  const int ncol = (wid >> 1) * 64;        // 0 or 64 (co group within 128)

  __shared__ __align__(16) f16 Al[720 * 8];    // [r0..9][seg0..3][px0..17]
  __shared__ __align__(16) f16 Bl[3072 * 8];   // taps 0..5: [tap][s0..3][co0..127]

  f32x4 acc[4][4];
#pragma unroll
  for (int i = 0; i < 4; ++i)
#pragma unroll
    for (int j = 0; j < 4; ++j) acc[i][j] = (f32x4){0.f, 0.f, 0.f, 0.f};

  const f16* inb = in + (size_t)(b * PTOT + pbase) * 256;

  for (int cb = 0; cb < 8; ++cb) {
    __syncthreads();              // all reads of Al/Bl for cb-1 done
    // DMA A: 720 units; unit u -> r=u/72, s=(u%72)/18, px=u%18
#pragma unroll
    for (int it = 0; it < 3; ++it) {
      int u = tid + it * 256;
      if (u < 720) {
        int r = u / 72, rem = u - r * 72;
        int s = rem / 18, px = rem - s * 18;
        cp16_g2l(inb + ((size_t)(y0 + r) * Wp + x0 + px) * 256 + cb * 32 + s * 8,
                 Al + (size_t)u * 8);
      }
    }
    // DMA B taps 0..5: 3072 units; unit u -> tapS=u>>7, co=u&127
#pragma unroll
    for (int it = 0; it < 12; ++it) {
      int u = tid + it * 256;
      int tapS = u >> 7, col = u & 127;
      int tap = tapS >> 2, s = tapS & 3;
      cp16_g2l(wB + (((size_t)(tap * 32 + cb * 4 + s)) * 256 + cog * 128 + col) * 8,
               Bl + (size_t)u * 8);
    }
    __syncthreads();              // DMA drained (compiler emits vmcnt(0))

#pragma unroll
    for (int kx = 0; kx < 3; ++kx) {
      f16x8 rowv[6];              // A rows mrow..mrow+5 at this kx (reg cache)
#pragma unroll
      for (int rr = 0; rr < 6; ++rr)
        rowv[rr] = *(const f16x8*)(Al + (size_t)(((mrow + rr) * 4 + q) * 18 + m + kx) * 8);
#pragma unroll
      for (int ky = 0; ky < 3; ++ky) {
        const int tap = ky * 3 + kx;
        f16x8 bf[4];
        if (ky < 2) {             // LDS-staged taps 0..5
#pragma unroll
          for (int nb = 0; nb < 4; ++nb)
            bf[nb] = *(const f16x8*)(Bl + (size_t)((tap * 4 + q) * 128 + ncol + nb * 16 + m) * 8);
        } else {                  // taps 6..8 direct from L2
#pragma unroll
          for (int nb = 0; nb < 4; ++nb)
            bf[nb] = *(const f16x8*)(wB + (((size_t)(tap * 32 + cb * 4 + q)) * 256 + cog * 128 + ncol + nb * 16 + m) * 8);
        }
#pragma unroll
        for (int mb = 0; mb < 4; ++mb)
#pragma unroll
          for (int nb = 0; nb < 4; ++nb)
            acc[mb][nb] = __builtin_amdgcn_mfma_f32_16x16x32_f16(rowv[mb + ky], bf[nb], acc[mb][nb], 0, 0, 0);
      }
    }
  }

  // epilogue: D row (q*4+r) = x-offset, col (m) = co; write padded interior
  f16* outb = out + (size_t)(b * PTOT + pbase) * 256;
#pragma unroll
  for (int mb = 0; mb < 4; ++mb) {
    int y = y0 + mrow + mb;
    if (y >= H) continue;
#pragma unroll
    for (int nb = 0; nb < 4; ++nb) {
      int co = cog * 128 + ncol + nb * 16 + m;
      float bi = bias[co];
#pragma unroll
      for (int r = 0; r < 4; ++r) {
        int x = x0 + q * 4 + r;
        if (x < W) {
          float v = fmaxf(acc[mb][nb][r] + bi, 0.f);
          outb[((size_t)(y + 1) * Wp + x + 1) * 256 + co] = (f16)v;
        }
      }
    }
  }
}

// ---------------------------------------------------------------------------
// Merged MFMA head pairs, NO LDS / NO BARRIERS. grid (84, 2, 2), block 256.
// ---------------------------------------------------------------------------
__global__ __launch_bounds__(256) void conv_mfma_head3(
    const f16* __restrict__ in_cls, const f16* __restrict__ in_box,
    const f16* __restrict__ wH, const float* __restrict__ hb,
    float* __restrict__ cls_prob, float* __restrict__ num_prob,
    float* __restrict__ offsets, float* __restrict__ iou_prob)
{
  int lv, y0, x0;
  get_tile16(blockIdx.x, lv, y0, x0);
  const int H = LV_H[lv], W = LV_W[lv], Wp = W + 2, pbase = LV_PB[lv];
  const int b = blockIdx.y, z = blockIdx.z;
  const f16* in = z ? in_box : in_cls;
  const f16* wB = wH + (size_t)z * 2304 * 32;   // [tap][s][co32][8]
  const float* hbz = hb + z * 32;
  float* o1 = z ? offsets : cls_prob;
  float* o2 = z ? iou_prob : num_prob;
  const int C1 = z ? 24 : 6, P1 = z ? 8 : 2, SIG = z ? 0 : 1;

  const int tid = threadIdx.x;
  const int lane = tid & 63, wid = tid >> 6;
  const int m = lane & 15, q = lane >> 4;

  f32x4 acc[4][2];
#pragma unroll
  for (int i = 0; i < 4; ++i) { acc[i][0] = (f32x4){0,0,0,0}; acc[i][1] = (f32x4){0,0,0,0}; }

  const f16* inb = in + (size_t)(b * PTOT + pbase) * 256;
  const f16* pA = inb + ((size_t)(y0 + wid * 4) * Wp + x0 + m) * 256 + q * 8;
  const f16* pB = wB + ((size_t)q * 32 + m) * 8;

  for (int cb = 0; cb < 8; ++cb) {
    const f16* pAc = pA + cb * 32;
    const f16* pBc = pB + (size_t)cb * 4 * 32 * 8;
#pragma unroll
    for (int tap = 0; tap < 9; ++tap) {
      const int ky = tap / 3, kx = tap - ky * 3;
      f16x8 af[4], bf[2];
#pragma unroll
      for (int mb = 0; mb < 4; ++mb)
        af[mb] = *(const f16x8*)(pAc + ((size_t)(mb + ky) * Wp + kx) * 256);
#pragma unroll
      for (int nb = 0; nb < 2; ++nb)
        bf[nb] = *(const f16x8*)(pBc + (size_t)tap * 8192 + nb * 128);
#pragma unroll
      for (int mb = 0; mb < 4; ++mb)
#pragma unroll
        for (int nb = 0; nb < 2; ++nb)
          acc[mb][nb] = __builtin_amdgcn_mfma_f32_16x16x32_f16(af[mb], bf[nb], acc[mb][nb], 0, 0, 0);
    }
  }

  const int robase = (lv == 0 ? 0 : lv == 1 ? 60 : lv == 2 ? 300 : lv == 3 ? 1260 : 5100) * 3;
#pragma unroll
  for (int mb = 0; mb < 4; ++mb) {
    int y = y0 + wid * 4 + mb;
    if (y >= H) continue;
#pragma unroll
    for (int nb = 0; nb < 2; ++nb) {
      int j = nb * 16 + m;
      if (j >= C1 + 6) continue;
      float bi = hbz[j];
#pragma unroll
      for (int r = 0; r < 4; ++r) {
        int x = x0 + q * 4 + r;
        if (x < W) {
          float v = acc[mb][nb][r] + bi;
          int row0 = robase + (y * W + x) * 3;
          if (j < C1) {
            if (SIG) v = 1.f / (1.f + expf(-v));
            int jd = j / P1;
            o1[((size_t)b * A_TOTAL + row0 + jd) * P1 + (j - jd * P1)] = v;
          } else {
            int jj = j - C1;
            o2[((size_t)b * A_TOTAL + row0 + (jj >> 1)) * 2 + (jj & 1)] = v;
          }
        }
      }
    }
  }
}

// ---------------------------------------------------------------------------
// Anchor generation (exact in fp32); also zeroes the loss accumulator.
// ---------------------------------------------------------------------------
__global__ void gen_anchors(float* __restrict__ anchors, float* __restrict__ accum)
{
  int i = blockIdx.x * 256 + threadIdx.x;
  if (blockIdx.x == 0 && threadIdx.x < 8) accum[threadIdx.x] = 0.f;
  if (i >= A_TOTAL) return;
  int off, s, Wl;
  if (i >= 15300)     { off = 15300; s = 8;   Wl = 160; }
  else if (i >= 3780) { off = 3780;  s = 16;  Wl = 80;  }
  else if (i >= 900)  { off = 900;   s = 32;  Wl = 40;  }
  else if (i >= 180)  { off = 180;   s = 64;  Wl = 20;  }
  else                { off = 0;     s = 128; Wl = 10;  }
  int r = i - off;
  int cell = r / 3, a = r - cell * 3;
  int y = cell / Wl, x = cell - y * Wl;
  float wsv = (a == 0) ? 4.f : (a == 1) ? 3.f : 2.f;
  float hsv = (a == 0) ? 4.f : 6.f;
  float sw = wsv * (float)s, sh = hsv * (float)s;
  float cx = (float)(x * s) + 1.5f, cy = (float)(y * s) + 1.5f;
  anchors[i * 4 + 0] = cx - 0.5f * (sw - 1.f);
  anchors[i * 4 + 1] = cy - 0.5f * (sh - 1.f);
  anchors[i * 4 + 2] = cx + 0.5f * (sw - 1.f);
  anchors[i * 4 + 3] = cy + 0.5f * (sh - 1.f);
}

__global__ __launch_bounds__(256) void anchor_target(
    const float* __restrict__ anchors, const float* __restrict__ gt,
    const float* __restrict__ iminfo, float* __restrict__ rpn, float* __restrict__ tgt)
{
  int i = blockIdx.x * 256 + threadIdx.x;
  int b = blockIdx.y;
  if (i >= A_TOTAL) return;
  float cnt = iminfo[b * 6 + 5];
  float ax1 = anchors[i*4+0], ay1 = anchors[i*4+1], ax2 = anchors[i*4+2], ay2 = anchors[i*4+3];
  float aw = ax2 - ax1 + 1.f, ah = ay2 - ay1 + 1.f, ab = aw * ah;
  float v1 = -1e30f, v2 = -1e30f; int i1 = 0, i2 = 0;
  for (int g = 0; g < NGT; ++g) {
    const float* gp = gt + (b * NGT + g) * 5;
    float ov = -1.f;
    if ((float)g < cnt && gp[4] != -1.f) {
      float iw = fmaxf(fminf(ax2, gp[2]) - fmaxf(ax1, gp[0]) + 1.f, 0.f);
      float ih = fmaxf(fminf(ay2, gp[3]) - fmaxf(ay1, gp[1]) + 1.f, 0.f);
      float inter = iw * ih;
      float ag = (gp[2] - gp[0] + 1.f) * (gp[3] - gp[1] + 1.f);
      ov = inter / (ab + ag - inter);
    }
    if (ov > v1)      { v2 = v1; i2 = i1; v1 = ov; i1 = g; }
    else if (ov > v2) { v2 = ov; i2 = g; }
  }
  float l1 = (v1 >= 0.5f) ? 1.f : ((v1 < 0.4f) ? 0.f : -1.f);
  float l2 = (v2 >= 0.5f) ? 1.f : ((v2 < 0.4f) ? 0.f : -1.f);
  rpn[(b * A_TOTAL + i) * 2 + 0] = l1;
  rpn[(b * A_TOTAL + i) * 2 + 1] = l2;
  float acx = ax1 + 0.5f * (aw - 1.f), acy = ay1 + 0.5f * (ah - 1.f);
  int idx2[2] = {i1, i2};
#pragma unroll
  for (int k = 0; k < 2; ++k) {
    const float* gp = gt + (b * NGT + idx2[k]) * 5;
    float gw = gp[2] - gp[0] + 1.f, gh = gp[3] - gp[1] + 1.f;
    float gcx = gp[0] + 0.5f * (gw - 1.f), gcy = gp[1] + 0.5f * (gh - 1.f);
    float* o = tgt + ((size_t)(b * 2 * A_TOTAL) + i * 2 + k) * 4;
    o[0] = (gcx - acx) / aw;  o[1] = (gcy - acy) / ah;
    o[2] = logf(gw / aw);     o[3] = logf(gh / ah);
  }
}

__global__ __launch_bounds__(256) void iou_target(
    const float* __restrict__ anchors, const float* __restrict__ gt,
    const float* __restrict__ iminfo, const float* __restrict__ offsets,
    float* __restrict__ ioust)
{
  int i = blockIdx.x * 256 + threadIdx.x;
  int b = blockIdx.y;
  if (i >= A_TOTAL) return;
  float cnt = iminfo[b * 6 + 5];
  float ax1 = anchors[i*4+0], ay1 = anchors[i*4+1], ax2 = anchors[i*4+2], ay2 = anchors[i*4+3];
  float aw = ax2 - ax1 + 1.f, ah = ay2 - ay1 + 1.f;
  float acx = ax1 + 0.5f * (aw - 1.f), acy = ay1 + 0.5f * (ah - 1.f);
  const float mx = 4.135166556742356f;
  float bx[2][4];
#pragma unroll
  for (int k = 0; k < 2; ++k) {
    const float* d = offsets + ((size_t)(b * A_TOTAL) + i) * 8 + k * 4;
    float pw = expf(fminf(d[2], mx)) * aw;
    float ph = expf(fminf(d[3], mx)) * ah;
    float pcx = d[0] * aw + acx, pcy = d[1] * ah + acy;
    bx[k][0] = pcx - 0.5f * (pw - 1.f); bx[k][1] = pcy - 0.5f * (ph - 1.f);
    bx[k][2] = pcx + 0.5f * (pw - 1.f); bx[k][3] = pcy + 0.5f * (ph - 1.f);
  }
  float area0 = (bx[0][2]-bx[0][0]+1.f) * (bx[0][3]-bx[0][1]+1.f);
  float area1 = (bx[1][2]-bx[1][0]+1.f) * (bx[1][3]-bx[1][1]+1.f);
  float av = -1e30f; int i1 = 0;
  for (int g = 0; g < NGT; ++g) {
    const float* gp = gt + (b * NGT + g) * 5;
    float keep = ((float)g < cnt && gp[4] != -1.f) ? 1.f : 0.f;
    float ag = (gp[2] - gp[0] + 1.f) * (gp[3] - gp[1] + 1.f);
    float iw = fmaxf(fminf(bx[0][2], gp[2]) - fmaxf(bx[0][0], gp[0]) + 1.f, 0.f);
    float ih = fmaxf(fminf(bx[0][3], gp[3]) - fmaxf(bx[0][1], gp[1]) + 1.f, 0.f);
    float inter = iw * ih;
    float ov = inter / (area0 + ag - inter) * keep;
    if (ov > av) { av = ov; i1 = g; }
  }
  float bv = -1e30f;
  for (int g = 0; g < NGT; ++g) {
    float val = 0.f;
    if (g != i1) {
      const float* gp = gt + (b * NGT + g) * 5;
      float keep = ((float)g < cnt && gp[4] != -1.f) ? 1.f : 0.f;
      float ag = (gp[2] - gp[0] + 1.f) * (gp[3] - gp[1] + 1.f);
      float iw = fmaxf(fminf(bx[1][2], gp[2]) - fmaxf(bx[1][0], gp[0]) + 1.f, 0.f);
      float ih = fmaxf(fminf(bx[1][3], gp[3]) - fmaxf(bx[1][1], gp[1]) + 1.f, 0.f);
      float inter = iw * ih;
      val = inter / (area1 + ag - inter) * keep;
    }
    bv = fmaxf(bv, val);
  }
  ioust[(b * A_TOTAL + i) * 2 + 0] = av;
  ioust[(b * A_TOTAL + i) * 2 + 1] = bv;
}

__global__ __launch_bounds__(256) void loss_reduce(
    const float* __restrict__ cls_prob, const float* __restrict__ num_prob,
    const float* __restrict__ offsets,  const float* __restrict__ iou_prob,
    const float* __restrict__ rpn,      const float* __restrict__ tgt,
    const float* __restrict__ ioust,    float* __restrict__ accum)
{
  int i = blockIdx.x * 256 + threadIdx.x;
  int b = blockIdx.y;
  float cls_s = 0.f, npos = 0.f, bb_s = 0.f, iou_s = 0.f, num_s = 0.f, num_c = 0.f;
  float la = 0.f, ign = 0.f;
  if (i < A_TOTAL) {
    int base = b * A_TOTAL + i;
    la = rpn[base * 2 + 0];
    float lb = rpn[base * 2 + 1];
    ign = lb - ((la == 0.f && lb != 0.f) ? 1.f : 0.f);
    float lab2[2] = {la, ign};
#pragma unroll
    for (int j = 0; j < 2; ++j) {
      float l = lab2[j];
      float mask = (l != -1.f) ? 1.f : 0.f;
      bool oh = (l * mask) == 1.f;
      float p = cls_prob[base * 2 + j];
      float term = oh ? (0.25f * (1.f - p) * (1.f - p) * logf(p))
                      : (0.75f * p * p * logf(1.f - p));
      cls_s += -term * mask;
      if (l > 0.f) {
        npos += 1.f;
#pragma unroll
        for (int c = 0; c < 4; ++c) {
          float d = offsets[(size_t)base * 8 + j * 4 + c]
                  - tgt[((size_t)(b * 2 * A_TOTAL) + i * 2 + j) * 4 + c];
          float ad = fabsf(d);
          bb_s += (ad < 1.f / 9.f) ? (4.5f * d * d) : (ad - 0.5f / 9.f);
        }
        iou_s += fabsf(iou_prob[base * 2 + j] - ioust[base * 2 + j]);
      }
    }
    int nl = ((la > 0.f) ? 1 : 0) + ((ign > 0.f) ? 1 : 0) - 1;
    if (nl != -1) {
      float s0 = num_prob[base * 2], s1 = num_prob[base * 2 + 1];
      float mm = fmaxf(s0, s1);
      float lse = mm + logf(expf(s0 - mm) + expf(s1 - mm));
      num_s += lse - ((nl == 0) ? s0 : s1);
      num_c += 1.f;
    }
  }
  __shared__ float red[6][4];
  float vals[6] = {cls_s, npos, bb_s, iou_s, num_s, num_c};
  int lane = threadIdx.x & 63, wid = threadIdx.x >> 6;
#pragma unroll
  for (int qq = 0; qq < 6; ++qq) {
    float v = vals[qq];
#pragma unroll
    for (int o = 32; o > 0; o >>= 1) v += __shfl_down(v, o);
    if (lane == 0) red[qq][wid] = v;
  }
  __syncthreads();
  if (threadIdx.x < 6) {
    float s = red[threadIdx.x][0] + red[threadIdx.x][1] + red[threadIdx.x][2] + red[threadIdx.x][3];
    atomicAdd(&accum[threadIdx.x], s);
  }
}

__global__ void finalize_loss(const float* __restrict__ acc, float* __restrict__ out)
{
  float npos = fmaxf(acc[1], 1.f);
  out[0] = acc[0] / npos;
  out[1] = 2.f * acc[2] / npos;
  out[2] = 2.f * acc[3] / npos;
  out[3] = acc[4] / fmaxf(acc[5], 1.f);
}

// ---------------------------------------------------------------------------
extern "C" void kernel_launch(void* const* d_in, const int* in_sizes, int n_in,
                              void* d_out, int out_size, void* d_ws, size_t ws_size,
                              hipStream_t stream)
{
  (void)in_sizes; (void)n_in; (void)out_size; (void)ws_size;
  const float* feat[5];
  for (int i = 0; i < 5; ++i) feat[i] = (const float*)d_in[i];
  const float* gt      = (const float*)d_in[5];
  const float* iminfo  = (const float*)d_in[6];
  const float* cls_w   = (const float*)d_in[7];
  const float* cls_b   = (const float*)d_in[8];
  const float* box_w   = (const float*)d_in[9];
  const float* box_b   = (const float*)d_in[10];
  const float* score_w = (const float*)d_in[11];
  const float* score_b = (const float*)d_in[12];
  const float* bpred_w = (const float*)d_in[13];
  const float* bpred_b = (const float*)d_in[14];
  const float* iou_w   = (const float*)d_in[15];
  const float* iou_b   = (const float*)d_in[16];
  const float* num_w   = (const float*)d_in[17];
  const float* num_b   = (const float*)d_in[18];

  const size_t ACT2 = (size_t)2 * PTOT * 256;      // padded activations, n=2
  f16* actF = (f16*)d_ws;                          // feats / box ping
  f16* actA = actF + ACT2;                         // cls ping (aliased later)
  f16* actB = actA + ACT2;                         // cls pong (cls tower out)
  f16* actC = actB + ACT2;                         // box pong
  f16* wT   = actC + ACT2;                         // 8*2304*256 f16
  f16* wH   = wT + (size_t)8 * 2304 * 256;         // 2*2304*32 f16
  float* hb = (float*)(wH + (size_t)2 * 2304 * 32);// 64 f32

  // loss-side buffers aliased into actA (dead after tower layer 3)
  float* cls_prob = (float*)actA;                  // 2*A*2
  float* num_prob = cls_prob + 2 * A_TOTAL * 2;
  float* offsets  = num_prob + 2 * A_TOTAL * 2;    // 2*A*8
  float* iou_prob = offsets + 2 * A_TOTAL * 8;
  float* anchors  = iou_prob + 2 * A_TOTAL * 2;    // A*4
  float* rpn      = anchors + A_TOTAL * 4;         // 2*A*2
  float* tgt      = rpn + 2 * A_TOTAL * 2;         // 2*2A*4
  float* ioust    = tgt + 2 * 2 * A_TOTAL * 4;     // 2*A*2
  float* accum    = ioust + 2 * A_TOTAL * 2;       // 8

  prep_tower_w3<<<dim3(2048), 256, 0, stream>>>(cls_w, box_w, wT);
  prep_head_w3<<<dim3(72), 256, 0, stream>>>(
      score_w, num_w, bpred_w, iou_w, score_b, num_b, bpred_b, iou_b, wH, hb);
  zero_borders<<<dim3(1012, 2, 4), 64, 0, stream>>>(actF);
  feats_to_nhwc<<<dim3(640, 8, 2), 256, 0, stream>>>(
      feat[0], feat[1], feat[2], feat[3], feat[4], actF);

  // merged towers: cls chain F->A->B->A->B ; box chain F->C->F->C->F
  dim3 tg(164, 2, 4);
  conv_mfma_tower5<<<tg, 256, 0, stream>>>(actF, actA, actF, actC, wT, cls_b, box_b, 0);
  conv_mfma_tower5<<<tg, 256, 0, stream>>>(actA, actB, actC, actF, wT, cls_b, box_b, 1);
  conv_mfma_tower5<<<tg, 256, 0, stream>>>(actB, actA, actF, actC, wT, cls_b, box_b, 2);
  conv_mfma_tower5<<<tg, 256, 0, stream>>>(actA, actB, actC, actF, wT, cls_b, box_b, 3);

  // merged heads: cls tower out = actB, box tower out = actF
  conv_mfma_head3<<<dim3(84, 2, 2), 256, 0, stream>>>(
      actB, actF, wH, hb, cls_prob, num_prob, offsets, iou_prob);

  dim3 agrid((A_TOTAL + 255) / 256, 2);
  gen_anchors<<<dim3((A_TOTAL + 255) / 256), 256, 0, stream>>>(anchors, accum);
  anchor_target<<<agrid, 256, 0, stream>>>(anchors, gt, iminfo, rpn, tgt);
  iou_target<<<agrid, 256, 0, stream>>>(anchors, gt, iminfo, offsets, ioust);
  loss_reduce<<<agrid, 256, 0, stream>>>(cls_prob, num_prob, offsets, iou_prob,
                                         rpn, tgt, ioust, accum);
  finalize_loss<<<1, 1, 0, stream>>>(accum, (float*)d_out);
}